// Round 6
// baseline (308.900 us; speedup 1.0000x reference)
//
#include <hip/hip_runtime.h>

#define Bdim 256
#define Tdim 512
#define Kdim 128
#define NT   1024  // thread (jc = tid>>4, g = tid&15): 2 columns x 8-row slice

// Raw barrier: drain LDS ops only (NOT vmcnt) so global prefetches stay in
// flight across steps; then s_barrier. "memory" stops compiler reordering.
#define BAR() asm volatile("s_waitcnt lgkmcnt(0)\n\ts_barrier" ::: "memory")

// DPP butterfly add. 0xB1 = quad_perm [1,0,3,2] (xor 1); 0x4E = [2,3,0,1]
// (xor 2); 0x124 = row_ror:4; 0x128 = row_ror:8 (rows are 16 lanes).
// quad(xor1)+quad(xor2)+ror4+ror8 sums all 16 lanes of each row.
template <int CTRL>
__device__ __forceinline__ float dpp_add(float v) {
    int r = __builtin_amdgcn_update_dpp(0, __float_as_int(v), CTRL, 0xF, 0xF, true);
    return v + __int_as_float(r);
}

// One block per batch element, 1024 threads (16 waves).
// Thread (jc, g) accumulates columns {2jc, 2jc+1} over rows [8g, 8g+8):
// 16 FMAs on an 8x2 E-fragment (16 VGPRs). Peak live set ~42 VGPRs —
// deliberately below the ~44-48 the allocator granted in rounds 3-5, where
// larger fragments were silently remat'd/spilled into the step loop
// (VGPR_Count < fragment size every round; that, not DS traffic, was the
// ~930cy/step cost). Reduce over the 16 g-groups entirely in DPP.
// alpha in LINEAR space, renormalized by A[0] each step.
__global__ __launch_bounds__(NT, 1) void crf_nll_kernel(
    const float* __restrict__ logits,   // B*T*K fp32
    const int*   __restrict__ labels,   // B*T   int32
    const int*   __restrict__ seq_lens, // B     int32
    const float* __restrict__ trans,    // K*K   fp32
    float* __restrict__ out)            // 1     fp32 (pre-zeroed)
{
    const int b   = blockIdx.x;
    const int tid = threadIdx.x;
    const int jc  = tid >> 4;           // column pair 0..63 (cols 2jc, 2jc+1)
    const int g   = tid & 15;           // row-slice group 0..15
    const int cj  = 2 * jc + (g & 1);   // this lane's write/logit column
    const int L   = seq_lens[b];        // 1..T (uniform per block)

    __shared__ float pbuf[2][Kdim];
    __shared__ float sred[NT / 64];
    __shared__ float ared[NT / 64];

    const int*   lab_b   = labels + (size_t)b * Tdim;
    const float* logit_b = logits + (size_t)b * Tdim * Kdim;

    // ---- E fragment (8 rows x 2 cols). Read-instruction ii accesses float4
    // index f = 2g + (((g>>2)&1)^ii): the 16 distinct addresses per inst
    // cover the 8 bank-quads exactly twice (2-way aliasing = free, m136).
    float e[2][4][2];
    #pragma unroll
    for (int ii = 0; ii < 2; ++ii) {
        const int f = (g << 1) + (((g >> 2) & 1) ^ ii);
        #pragma unroll
        for (int ci = 0; ci < 4; ++ci) {
            const float2 tr =
                *(const float2*)&trans[(size_t)(4 * f + ci) * Kdim + 2 * jc];
            e[ii][ci][0] = __expf(tr.x);
            e[ii][ci][1] = __expf(tr.y);
        }
    }

    // ---- gold-path score: thread t = tid handles one timestep (tid<512) ----
    float s = 0.f;
    {
        const int t = tid;
        if (t < L) {
            const int lb = lab_b[t];
            s = logit_b[(size_t)t * Kdim + lb];
            if (t >= 1) s += trans[lab_b[t - 1] * Kdim + lb];
        }
    }
    #pragma unroll
    for (int o = 32; o > 0; o >>= 1) s += __shfl_down(s, o, 64);
    if ((tid & 63) == 0) sred[tid >> 6] = s;

    // ---- init alpha (t = 0), linear space; g<2 lanes own a column ----
    float a = 0.f, off = 0.f;
    if (g < 2) {
        a = __expf(logit_b[cj]);
        pbuf[0][cj] = a;
    }
    int cb = 0;
    __syncthreads();

    float score = 0.f;
    if (tid == 0) {
        #pragma unroll
        for (int w = 0; w < NT / 64; ++w) score += sred[w];
    }

    // ---- prefetch first logit chunk (t = 1..4), this lane's column ----
    float curl[4], nxtl[4];
    #pragma unroll
    for (int u = 0; u < 4; ++u) {
        const int tt = 1 + u;
        curl[u] = (tt < Tdim) ? logit_b[(size_t)tt * Kdim + cj] : 0.f;
    }

    // ---- forward recursion ----
    for (int tb = 1; tb < L; tb += 4) {
        #pragma unroll
        for (int u = 0; u < 4; ++u) {        // prefetch next chunk
            const int tt = tb + 4 + u;
            nxtl[u] = (tt < Tdim) ? logit_b[(size_t)tt * Kdim + cj] : 0.f;
        }
        #pragma unroll
        for (int u = 0; u < 4; ++u) {
            const int t = tb + u;
            if (t < L) {                     // uniform per block
                const float4* p4 = (const float4*)pbuf[cb];
                const float p0  = pbuf[cb][0];       // uniform broadcast read
                const float lp0 = __logf(p0);        // off critical path
                const float sc  = __expf(curl[u] - lp0);
                float acc0 = 0.f, acc1 = 0.f;
                #pragma unroll
                for (int ii = 0; ii < 2; ++ii) {
                    const float4 p = p4[(g << 1) + (((g >> 2) & 1) ^ ii)];
                    acc0 = fmaf(p.x, e[ii][0][0], acc0);
                    acc1 = fmaf(p.x, e[ii][0][1], acc1);
                    acc0 = fmaf(p.y, e[ii][1][0], acc0);
                    acc1 = fmaf(p.y, e[ii][1][1], acc1);
                    acc0 = fmaf(p.z, e[ii][2][0], acc0);
                    acc1 = fmaf(p.z, e[ii][2][1], acc1);
                    acc0 = fmaf(p.w, e[ii][3][0], acc0);
                    acc1 = fmaf(p.w, e[ii][3][1], acc1);
                }
                off += lp0;
                // 16-lane butterfly per accumulator, pure DPP (no DS pipe)
                acc0 = dpp_add<0xB1>(acc0); acc0 = dpp_add<0x4E>(acc0);
                acc0 = dpp_add<0x124>(acc0); acc0 = dpp_add<0x128>(acc0);
                acc1 = dpp_add<0xB1>(acc1); acc1 = dpp_add<0x4E>(acc1);
                acc1 = dpp_add<0x124>(acc1); acc1 = dpp_add<0x128>(acc1);
                // lane's column (c = g&1)
                const float sel  = (g & 1) ? acc1 : acc0;
                const float anew = sel * sc;
                if (g < 2) {
                    a = anew;
                    pbuf[cb ^ 1][cj] = anew;
                }
                cb ^= 1;
                BAR();                       // lgkm-only barrier per step
            }
        }
        #pragma unroll
        for (int u = 0; u < 4; ++u) curl[u] = nxtl[u];
    }

    // ---- log_z = off + log(sum_j A[j]); nll = log_z - score ----
    float as = (g < 2) ? a : 0.f;
    #pragma unroll
    for (int o = 32; o > 0; o >>= 1) as += __shfl_down(as, o, 64);
    if ((tid & 63) == 0) ared[tid >> 6] = as;
    __syncthreads();
    if (tid == 0) {
        float tot = 0.f;
        #pragma unroll
        for (int w = 0; w < NT / 64; ++w) tot += ared[w];
        const float logz = off + __logf(tot);
        atomicAdd(out, logz - score);
    }
}

extern "C" void kernel_launch(void* const* d_in, const int* in_sizes, int n_in,
                              void* d_out, int out_size, void* d_ws, size_t ws_size,
                              hipStream_t stream) {
    const float* logits   = (const float*)d_in[0];
    const int*   labels   = (const int*)d_in[1];
    const int*   seq_lens = (const int*)d_in[2];
    const float* trans    = (const float*)d_in[3];
    float* out = (float*)d_out;

    (void)hipMemsetAsync(out, 0, sizeof(float), stream);
    crf_nll_kernel<<<dim3(Bdim), dim3(NT), 0, stream>>>(
        logits, labels, seq_lens, trans, out);
}